// Round 1
// 400.784 us; speedup vs baseline: 1.0418x; 1.0418x over previous
//
#include <hip/hip_runtime.h>
#include <hip/hip_bf16.h>
#include <math.h>

// Problem constants (fixed by setup_inputs: B=4, L=2048)
#define BB      4
#define LL      2048
#define KNB     30
#define NRES    (BB*LL)          // 8192
#define NEDGE   (NRES*KNB)       // 245760
#define EDGE_IN 416              // 16 pos + 25*16 RBF = 13 * 32
#define KT      13               // K-tiles of 32
#define KTA     7                // pass-A k-tiles (features 0..223)
#define ME      32               // edges per block in edge kernel
#define AST2    232              // A-tile row stride in fp16 for 7-tile buffer (464 B, 16B-aligned, 2-way banks)

typedef __attribute__((ext_vector_type(8))) _Float16 half8;
typedef __attribute__((ext_vector_type(4))) float floatx4;

__device__ __constant__ int d_PA[25] = {0,1,2,3,4,0,0,0,0,1,1,1,4,4,3,1,2,3,4,2,3,4,2,3,2};
__device__ __constant__ int d_PB[25] = {0,1,2,3,4,1,2,3,4,2,3,4,2,3,2,0,0,0,0,1,1,1,4,4,3};

__device__ __forceinline__ unsigned short f2h_bits(float x) {
    _Float16 h = (_Float16)x;
    union { _Float16 h; unsigned short u; } v; v.h = h;
    return v.u;
}
__device__ __forceinline__ unsigned pack2h(float a, float b) {
    return (unsigned)f2h_bits(a) | ((unsigned)f2h_bits(b) << 16);
}

// ---------------------------------------------------------------------------
// Kernel 1: per-residue atom construction.  atoms[r][5][3] = [Ca,N,C,O,Cb]
// ---------------------------------------------------------------------------
__global__ __launch_bounds__(256) void atoms_kernel(const float* __restrict__ X,
                                                    float* __restrict__ atoms) {
    int r = blockIdx.x * blockDim.x + threadIdx.x;
    if (r >= NRES) return;
    const float* xr = X + (size_t)r * 12;
    float Nx = xr[0],  Ny = xr[1],  Nz = xr[2];
    float Ax = xr[3],  Ay = xr[4],  Az = xr[5];   // Ca
    float Cx = xr[6],  Cy = xr[7],  Cz = xr[8];
    float Ox = xr[9],  Oy = xr[10], Oz = xr[11];
    float bx = Ax - Nx, by = Ay - Ny, bz = Az - Nz;
    float cx = Cx - Ax, cy = Cy - Ay, cz = Cz - Az;
    float ax = by * cz - bz * cy;
    float ay = bz * cx - bx * cz;
    float az = bx * cy - by * cx;
    float Cbx = -0.58273431f * ax + 0.56802827f * bx - 0.54067466f * cx + Ax;
    float Cby = -0.58273431f * ay + 0.56802827f * by - 0.54067466f * cy + Ay;
    float Cbz = -0.58273431f * az + 0.56802827f * bz - 0.54067466f * cz + Az;
    float* o = atoms + (size_t)r * 15;
    o[0]  = Ax;  o[1]  = Ay;  o[2]  = Az;
    o[3]  = Nx;  o[4]  = Ny;  o[5]  = Nz;
    o[6]  = Cx;  o[7]  = Cy;  o[8]  = Cz;
    o[9]  = Ox;  o[10] = Oy;  o[11] = Oz;
    o[12] = Cbx; o[13] = Cby; o[14] = Cbz;
}

// ---------------------------------------------------------------------------
// Kernel 2: top-K neighbor selection — ONE WAVE PER RESIDUE, REGISTER-RESIDENT.
// Distances bit-exact vs the fp32 numpy pipeline (contract off, same expr).
// Each lane holds 32 elements as u64 keys (float_bits<<32 | j): positive-float
// bit order is monotone, j makes keys unique => exact lexicographic (value, j)
// ordering incl. tie-break.  Per-lane bitonic sort (240 CEs, fully unrolled,
// register-indexed) then 30 rounds of {u64 butterfly min over lane heads +
// winner shift-pop}.  No LDS, no serial 32-deep compare chains.
// ---------------------------------------------------------------------------
__global__ __launch_bounds__(256, 4) void topk_kernel(const float* __restrict__ X,
                                                      const float* __restrict__ mask,
                                                      int* __restrict__ E_idx) {
#pragma clang fp contract(off)
    int t    = threadIdx.x;
    int wid  = t >> 6;
    int lane = t & 63;
    int bi   = blockIdx.x * 4 + wid;      // residue
    int b    = bi >> 11;
    int j0   = b << 11;

    const float* cai = X + ((size_t)bi * 4 + 1) * 3;
    float cx = cai[0], cy = cai[1], cz = cai[2];
    float mi = mask[bi];

    unsigned long long a[32];
    float lmax = 0.0f;
#pragma unroll
    for (int i = 0; i < 32; i++) {
        int j = i * 64 + lane;
        const float* cj = X + (((size_t)(j0 + j)) * 4 + 1) * 3;
        float dx = cx - cj[0], dy = cy - cj[1], dz = cz - cj[2];
        float ssq = ((dx * dx + dy * dy) + dz * dz) + 1e-6f;
        float m2  = mask[j0 + j] * mi;
        float Dj  = m2 * sqrtf(ssq);
        lmax = fmaxf(lmax, Dj);
        a[i] = ((unsigned long long)__float_as_uint(Dj) << 32) | (unsigned)j;
    }
    for (int off = 32; off; off >>= 1) lmax = fmaxf(lmax, __shfl_xor(lmax, off));
    // mask adjustment (exact no-op when mask==1); rebuild keys with adjusted value
#pragma unroll
    for (int i = 0; i < 32; i++) {
        int   j  = (int)(unsigned)(a[i] & 0xffffffffull);
        float Dj = __uint_as_float((unsigned)(a[i] >> 32));
        float m2 = mask[j0 + j] * mi;
        float adj = Dj + (1.0f - m2) * lmax;
        a[i] = ((unsigned long long)__float_as_uint(adj) << 32) | (unsigned)j;
    }

    // --- per-lane bitonic sort, ascending (compile-time indices only) ---
#pragma unroll
    for (int k = 2; k <= 32; k <<= 1) {
#pragma unroll
        for (int j = k >> 1; j > 0; j >>= 1) {
#pragma unroll
            for (int i = 0; i < 32; i++) {
                int ixj = i ^ j;
                if (ixj > i) {
                    bool up = ((i & k) == 0);
                    unsigned long long x = a[i], y = a[ixj];
                    bool sw = up ? (x > y) : (x < y);
                    a[i]   = sw ? y : x;
                    a[ixj] = sw ? x : y;
                }
            }
        }
    }

    // --- 30-round 64-way merge: butterfly min over heads, winner pops ---
    int* outp = E_idx + (size_t)bi * KNB;
    for (int r = 0; r < KNB; r++) {
        unsigned long long m = a[0];
        for (int off = 1; off < 64; off <<= 1) {
            unsigned long long o = __shfl_xor(m, off);
            m = (o < m) ? o : m;
        }
        if (lane == 0) outp[r] = (int)(unsigned)(m & 0xffffffffull);
        if (a[0] == m) {   // exactly one lane (keys unique)
#pragma unroll
            for (int i = 0; i < 31; i++) a[i] = a[i + 1];
            a[31] = ~0ull;
        }
    }
}

// ---------------------------------------------------------------------------
// Kernel 2.5: pre-swizzle W_edge (fp32 [416][128]) into SPLIT fp16 B-fragment
// order: Wh = fp16(W), Wl = fp16(W - Wh).  Layout [kk][nt][lane] of half8:
// element holds W[k = kk*32 + (lane>>4)*8 + j][n = nt*16 + (lane&15)].
// ---------------------------------------------------------------------------
__global__ __launch_bounds__(256) void wprep_kernel(const float* __restrict__ W_edge,
                                                    half8* __restrict__ Wfh,
                                                    half8* __restrict__ Wfl) {
    int t = blockIdx.x * blockDim.x + threadIdx.x;
    if (t >= KT * 8 * 64) return;
    int kk   = t >> 9;
    int rem  = t & 511;
    int nt   = rem >> 6;
    int lane = rem & 63;
    int n  = nt * 16 + (lane & 15);
    int kb = kk * 32 + (lane >> 4) * 8;
    half8 vh, vl;
#pragma unroll
    for (int j = 0; j < 8; j++) {
        float w = W_edge[(size_t)(kb + j) * 128 + n];
        _Float16 wh = (_Float16)w;
        vh[j] = wh;
        vl[j] = (_Float16)(w - (float)wh);
    }
    Wfh[t] = vh;
    Wfl[t] = vl;
}

// ---------------------------------------------------------------------------
// Kernel 3: edge featurization (SPLIT fp16 A-tile) + 3-term MFMA GEMM + LN.
// Block = 32 edges.  Wave w: edge strip (w&1)*16, feature half (w>>1)*64.
// E = Ah*Wh + Al*Wh + Ah*Wl  (fp32 accum; dropped Al*Wl ~ 2^-22) — effective
// fp32 GEMM precision at MFMA speed.
// K-dimension is time-split over a SINGLE half-size A buffer:
//   fill(k-tiles 0..6) -> GEMM -> refill(k-tiles 7..12) -> GEMM
// acc stays in registers across passes => accumulation order (and output)
// bit-identical to the full-buffer version.  LDS 58.4KB -> 33.7KB => 4
// blocks/CU instead of 2 (occupancy 22% -> ~44%) to hide the VALU/LDS latency.
// ---------------------------------------------------------------------------
__global__ __launch_bounds__(256) void edge_kernel(const float* __restrict__ atoms,
                                                   const int* __restrict__ E_idx,
                                                   const int* __restrict__ resi,
                                                   const float* __restrict__ W_pos,
                                                   const float* __restrict__ b_pos,
                                                   const half8* __restrict__ Wfh,
                                                   const half8* __restrict__ Wfl,
                                                   const float* __restrict__ gamma,
                                                   const float* __restrict__ beta,
                                                   float* __restrict__ out) {
    __shared__ _Float16 Ah[ME * AST2];             // 14848 B
    __shared__ _Float16 Al[ME * AST2];             // 14848 B
    __shared__ float Dl[ME][26];                   //  3328 B
    __shared__ float redS[2][ME];                  //   256 B
    __shared__ int   s_gi[ME], s_gj[ME], s_d[ME];  //   384 B

    int t  = threadIdx.x;
    int e0 = blockIdx.x * ME;

    if (t < ME) {
        int e  = e0 + t;
        int gi = e / KNB;
        int k  = e - gi * KNB;
        int b  = gi >> 11;
        int j  = E_idx[(size_t)gi * KNB + k];
        s_gi[t] = gi;
        s_gj[t] = (b << 11) + j;
        int off = resi[gi] - resi[(b << 11) + j];
        int d = off + 32;
        s_d[t] = d < 0 ? 0 : (d > 64 ? 64 : d);
    }
    __syncthreads();

    for (int idx = t; idx < ME * 25; idx += 256) {
        int e = idx / 25, p = idx - e * 25;
        const float* Ar = atoms + (size_t)s_gi[e] * 15 + d_PA[p] * 3;
        const float* Br = atoms + (size_t)s_gj[e] * 15 + d_PB[p] * 3;
        float dx = Ar[0] - Br[0];
        float dy = Ar[1] - Br[1];
        float dz = Ar[2] - Br[2];
        Dl[e][p] = sqrtf(dx * dx + dy * dy + dz * dz + 1e-6f);
    }
    __syncthreads();

    // --- fill pass A: features 0..223 (pos-emb + RBF pairs p=0..12) ---
    {
        int e  = t >> 3;           // 0..31
        int j8 = t & 7;
        const float* dle = Dl[e];
        _Float16* ah = &Ah[e * AST2];
        _Float16* al = &Al[e * AST2];
        if (j8 < 4) {              // pos-emb features c = j8*4 .. +3
            int c = j8 * 4;
            int dpos = s_d[e];
            const float* wp = W_pos + dpos * 16 + c;
            float v[4];
#pragma unroll
            for (int q = 0; q < 4; q++) v[q] = wp[q] + b_pos[c + q];
            float h0 = (float)(_Float16)v[0], h1 = (float)(_Float16)v[1];
            float h2 = (float)(_Float16)v[2], h3 = (float)(_Float16)v[3];
            *(unsigned*)&ah[c + 0] = pack2h(v[0], v[1]);
            *(unsigned*)&ah[c + 2] = pack2h(v[2], v[3]);
            *(unsigned*)&al[c + 0] = pack2h(v[0] - h0, v[1] - h1);
            *(unsigned*)&al[c + 2] = pack2h(v[2] - h2, v[3] - h3);
        }
        // RBF features: c2 = 2*(j8 + 8i), i = 0..12 — covers even 0..206
#pragma unroll
        for (int i = 0; i < 13; i++) {
            int c2 = 2 * (j8 + 8 * i);
            int p  = c2 >> 4;
            int r  = c2 & 15;
            float D = dle[p];
            float mu0 = 2.0f + (float)r * (20.0f / 15.0f);
            float mu1 = 2.0f + (float)(r + 1) * (20.0f / 15.0f);
            float t0 = (D - mu0) * 0.8f;
            float t1 = (D - mu1) * 0.8f;
            float g0 = expf(-t0 * t0);
            float g1 = expf(-t1 * t1);
            float h0 = (float)(_Float16)g0, h1 = (float)(_Float16)g1;
            *(unsigned*)&ah[16 + c2] = pack2h(g0, g1);
            *(unsigned*)&al[16 + c2] = pack2h(g0 - h0, g1 - h1);
        }
    }
    __syncthreads();

    // --- MFMA GEMM: 32x416 x 416x128 -> fp32, split precision, K time-split ---
    int lane  = t & 63;
    int w     = t >> 6;
    int strip = (w & 1) * 16;      // edge strip base
    int h     = w >> 1;            // feature half (0: n 0..63, 1: n 64..127)
    int m     = lane & 15;
    int quad  = lane >> 4;
    const _Float16* pah = &Ah[(strip + m) * AST2 + quad * 8];
    const _Float16* pal = &Al[(strip + m) * AST2 + quad * 8];

    floatx4 acc[4];
#pragma unroll
    for (int c = 0; c < 4; c++) acc[c] = (floatx4){0.f, 0.f, 0.f, 0.f};

    half8 bh[4], bl[4], bnh[4], bnl[4];
#pragma unroll
    for (int c = 0; c < 4; c++) {
        int idx = (h * 4 + c) * 64 + lane;
        bh[c] = Wfh[idx];
        bl[c] = Wfl[idx];
    }

    // pass A: k-tiles 0..6 (prefetch of kk+1 always valid: kk+1 <= 7)
#pragma unroll 1
    for (int kk = 0; kk < KTA; kk++) {
        half8 a_hi = *(const half8*)(pah + kk * 32);
        half8 a_lo = *(const half8*)(pal + kk * 32);
#pragma unroll
        for (int c = 0; c < 4; c++) {
            int idx = ((kk + 1) * 8 + h * 4 + c) * 64 + lane;
            bnh[c] = Wfh[idx];
            bnl[c] = Wfl[idx];
        }
#pragma unroll
        for (int c = 0; c < 4; c++) {
            acc[c] = __builtin_amdgcn_mfma_f32_16x16x32_f16(a_hi, bh[c], acc[c], 0, 0, 0);
            acc[c] = __builtin_amdgcn_mfma_f32_16x16x32_f16(a_lo, bh[c], acc[c], 0, 0, 0);
            acc[c] = __builtin_amdgcn_mfma_f32_16x16x32_f16(a_hi, bl[c], acc[c], 0, 0, 0);
        }
#pragma unroll
        for (int c = 0; c < 4; c++) { bh[c] = bnh[c]; bl[c] = bnl[c]; }
    }

    __syncthreads();   // all waves done reading buffer before overwrite

    // --- fill pass B: features 224..415 (RBF pairs p=13..24) into same buffer ---
    {
        int e  = t >> 3;
        int j8 = t & 7;
        const float* dle = Dl[e];
        _Float16* ah = &Ah[e * AST2];
        _Float16* al = &Al[e * AST2];
        // c2 = 2*(j8 + 8i), i = 13..24 — covers even 208..398; col = c2-208
#pragma unroll
        for (int i = 13; i < 25; i++) {
            int c2 = 2 * (j8 + 8 * i);
            int p  = c2 >> 4;
            int r  = c2 & 15;
            float D = dle[p];
            float mu0 = 2.0f + (float)r * (20.0f / 15.0f);
            float mu1 = 2.0f + (float)(r + 1) * (20.0f / 15.0f);
            float t0 = (D - mu0) * 0.8f;
            float t1 = (D - mu1) * 0.8f;
            float g0 = expf(-t0 * t0);
            float g1 = expf(-t1 * t1);
            float h0 = (float)(_Float16)g0, h1 = (float)(_Float16)g1;
            int col = c2 - 208;
            *(unsigned*)&ah[col] = pack2h(g0, g1);
            *(unsigned*)&al[col] = pack2h(g0 - h0, g1 - h1);
        }
    }
    __syncthreads();

    // pass B: k-tiles 7..12 (bh currently holds B(7) from pass-A pipeline)
#pragma unroll 1
    for (int kk = KTA; kk < KT; kk++) {
        half8 a_hi = *(const half8*)(pah + (kk - KTA) * 32);
        half8 a_lo = *(const half8*)(pal + (kk - KTA) * 32);
        if (kk < KT - 1) {
#pragma unroll
            for (int c = 0; c < 4; c++) {
                int idx = ((kk + 1) * 8 + h * 4 + c) * 64 + lane;
                bnh[c] = Wfh[idx];
                bnl[c] = Wfl[idx];
            }
        }
#pragma unroll
        for (int c = 0; c < 4; c++) {
            acc[c] = __builtin_amdgcn_mfma_f32_16x16x32_f16(a_hi, bh[c], acc[c], 0, 0, 0);
            acc[c] = __builtin_amdgcn_mfma_f32_16x16x32_f16(a_lo, bh[c], acc[c], 0, 0, 0);
            acc[c] = __builtin_amdgcn_mfma_f32_16x16x32_f16(a_hi, bl[c], acc[c], 0, 0, 0);
        }
#pragma unroll
        for (int c = 0; c < 4; c++) { bh[c] = bnh[c]; bl[c] = bnl[c]; }
    }

    // --- LayerNorm epilogue: per edge, features split across wave pairs ---
    // D[row = quad*4 + r][col = m]; edge_local = strip + quad*4 + r.
    int elb = strip + quad * 4;
    float sarr[4];
#pragma unroll
    for (int r = 0; r < 4; r++) {
        float s = acc[0][r] + acc[1][r] + acc[2][r] + acc[3][r];
        for (int msk = 1; msk <= 8; msk <<= 1) s += __shfl_xor(s, msk);
        sarr[r] = s;                       // this wave's 64-feature partial
    }
    if (m == 0) {
#pragma unroll
        for (int r = 0; r < 4; r++) redS[h][elb + r] = sarr[r];
    }
    __syncthreads();
    float mu[4];
#pragma unroll
    for (int r = 0; r < 4; r++) mu[r] = (redS[0][elb + r] + redS[1][elb + r]) * (1.0f / 128.0f);
    __syncthreads();
    float dvv[4][4];
#pragma unroll
    for (int r = 0; r < 4; r++) {
        float v = 0.f;
#pragma unroll
        for (int c = 0; c < 4; c++) { dvv[c][r] = acc[c][r] - mu[r]; v += dvv[c][r] * dvv[c][r]; }
        for (int msk = 1; msk <= 8; msk <<= 1) v += __shfl_xor(v, msk);
        if (m == 0) redS[h][elb + r] = v;
    }
    __syncthreads();
#pragma unroll
    for (int r = 0; r < 4; r++) {
        float var  = (redS[0][elb + r] + redS[1][elb + r]) * (1.0f / 128.0f);
        float rstd = rsqrtf(var + 1e-5f);
        int e = e0 + elb + r;
        float* orow = out + (size_t)e * 128;
#pragma unroll
        for (int c = 0; c < 4; c++) {
            int n = (h * 4 + c) * 16 + m;
            orow[n] = dvv[c][r] * rstd * gamma[n] + beta[n];
        }
    }
}

// ---------------------------------------------------------------------------
extern "C" void kernel_launch(void* const* d_in, const int* in_sizes, int n_in,
                              void* d_out, int out_size, void* d_ws, size_t ws_size,
                              hipStream_t stream) {
    const float* X      = (const float*)d_in[0];
    const float* mask   = (const float*)d_in[1];
    const int*   resi   = (const int*)  d_in[2];
    const float* W_pos  = (const float*)d_in[3];
    const float* b_pos  = (const float*)d_in[4];
    const float* W_edge = (const float*)d_in[5];
    const float* gamma  = (const float*)d_in[6];
    const float* beta   = (const float*)d_in[7];
    float* out = (float*)d_out;

    float* atoms = (float*)d_ws;                                     // 491520 B
    int*   E_idx = (int*)((char*)d_ws + (size_t)NRES * 15 * 4);      // 983040 B
    half8* Wfh   = (half8*)((char*)d_ws + 1474560);                  // 106496 B
    half8* Wfl   = (half8*)((char*)d_ws + 1581056);                  // 106496 B

    atoms_kernel<<<(NRES + 255) / 256, 256, 0, stream>>>(X, atoms);
    wprep_kernel<<<(KT * 8 * 64 + 255) / 256, 256, 0, stream>>>(W_edge, Wfh, Wfl);
    topk_kernel<<<NRES / 4, 256, 0, stream>>>(X, mask, E_idx);
    edge_kernel<<<NEDGE / ME, 256, 0, stream>>>(atoms, E_idx, resi,
                                                W_pos, b_pos, Wfh, Wfl, gamma, beta, out);
}